// Round 18
// baseline (990.841 us; speedup 1.0000x reference)
//
#include <hip/hip_runtime.h>

#define BB 8
#define NN 2048
#define WGS 1024
#define GRID 256
#define NWAVES 16
#define CHUNKS 32             // NN/64
#define MAX_ITER 50
#define NARR 64               // arrivals per batch barrier (32 prim + 32 sec WGs)

// eps = 0.005; log2 domain: SCL = log2(e)/eps
constexpr float SCL       = 288.5390081777927f;
constexpr float LN2f      = 0.6931471805599453f;
constexpr float EPSf      = 0.005f;
constexpr float EPS_LOGMU = -0.03812309493079699f; // 0.005 * (-ln 2048)

#define SCOPE __HIP_MEMORY_SCOPE_AGENT

__device__ __forceinline__ float aloadf(const float* p){return __hip_atomic_load(p,__ATOMIC_RELAXED,SCOPE);}
__device__ __forceinline__ void  astoref(float* p,float v){__hip_atomic_store(p,v,__ATOMIC_RELAXED,SCOPE);}
__device__ __forceinline__ int   aloadi(const int* p){return __hip_atomic_load(p,__ATOMIC_RELAXED,SCOPE);}

__device__ __forceinline__ float fexp2(float x){return __builtin_amdgcn_exp2f(x);}
__device__ __forceinline__ float flog2(float x){return __builtin_amdgcn_logf(x);}

__device__ __forceinline__ float wsum(float v){
  #pragma unroll
  for (int d = 32; d; d >>= 1) v += __shfl_xor(v, d, 64);
  return v;
}

// FLAG-ARRAY single-use barrier (r17-proven): arrivals are plain sc1 STORES
// to per-WG slots (no RMW serialization); waiters poll all 64 flags with one
// coalesced load per round. 0->1 monotone: no ABA/reuse races. Deadman
// converts any deadlock into a fast wrong answer, never a 600s hang.
__device__ __forceinline__ void flag_arrive(int* flags, int slot){
  __syncthreads();                     // all waves drain their sc1 pot stores
  if (threadIdx.x == 0) {
    asm volatile("s_waitcnt vmcnt(0)" ::: "memory");
    __hip_atomic_store(flags + slot, 1, __ATOMIC_RELAXED, SCOPE);
  }
}
__device__ __forceinline__ void flag_wait(const int* flags){
  if (threadIdx.x < 64) {
    const int* fp = flags + threadIdx.x;
    int spins = 0;
    while (!__all(aloadi(fp) != 0)) {
      __builtin_amdgcn_s_sleep(1);
      if (++spins > (1 << 17)) break;  // deadman
    }
  }
  __syncthreads();
}
// counter barrier for the single final global sync (latency-irrelevant)
__device__ __forceinline__ void sbar(int* cnt, int nwg){
  __syncthreads();
  if (threadIdx.x == 0) {
    asm volatile("s_waitcnt vmcnt(0)" ::: "memory");
    __hip_atomic_fetch_add(cnt, 1, __ATOMIC_RELAXED, SCOPE);
    int spins = 0;
    while (aloadi(cnt) < nwg) {
      __builtin_amdgcn_s_sleep(1);
      if (++spins > (1 << 17)) break;
    }
  }
  __syncthreads();
}

// One-time prep: pack {x,y,z,|p|^2}; zero 800x64 barrier flags + final
// counter + accum.
__global__ __launch_bounds__(256) void pack_pts(
    const float* __restrict__ pcs1, const float* __restrict__ pcs2,
    float4* __restrict__ rp1, float4* __restrict__ rp2,
    int* __restrict__ flags, float* __restrict__ accum)
{
  int idx = blockIdx.x * 256 + threadIdx.x;
  if (idx == 0) *accum = 0.f;
  if (idx < 800 * NARR + 16) flags[idx] = 0;
  if (idx >= 2 * BB * NN) return;
  if (idx < BB * NN) {
    const float* s = pcs1 + 3 * (size_t)idx;
    float x = s[0], y = s[1], z = s[2];
    rp1[idx] = make_float4(x, y, z, fmaf(x, x, fmaf(y, y, z * z)));
  } else {
    int j = idx - BB * NN;
    const float* s = pcs2 + 3 * (size_t)j;
    float x = s[0], y = s[1], z = s[2];
    rp2[j] = make_float4(x, y, z, fmaf(x, x, fmaf(y, y, z * z)));
  }
}

struct RowC { float X0x,X0y,X0z,B0, X1x,X1y,X1z,B1; };

__device__ __forceinline__ RowC mkRow(const float4* __restrict__ P, size_t bo, int i0){
  const float4 p0 = P[bo + i0], p1 = P[bo + i0 + 1];
  RowC r;
  r.X0x=2.f*SCL*p0.x; r.X0y=2.f*SCL*p0.y; r.X0z=2.f*SCL*p0.z; r.B0=-SCL*p0.w;
  r.X1x=2.f*SCL*p1.x; r.X1y=2.f*SCL*p1.y; r.X1z=2.f*SCL*p1.z; r.B1=-SCL*p1.w;
  return r;
}

// 2-row single-pass LSE sweep over one persistent column array (r15/r17
// proven M-free numerics: exp2 args in [+15,-890]; flushed terms lose
// <2^-80 relative; fmaxf backstop).
__device__ __forceinline__ void sweep2(
    const float4* __restrict__ J, const RowC rc,
    float* __restrict__ potOut, size_t bo, int i0, int lane)
{
  float s0 = 0.f, s1 = 0.f;
  #pragma unroll 4
  for (int k = 0; k < CHUNKS; ++k) {
    float4 q = J[k * 64 + lane];
    s0 += fexp2(fmaf(rc.X0x, q.x, fmaf(rc.X0y, q.y, fmaf(rc.X0z, q.z, q.w + rc.B0))));
    s1 += fexp2(fmaf(rc.X1x, q.x, fmaf(rc.X1y, q.y, fmaf(rc.X1z, q.z, q.w + rc.B1))));
  }
  const float S0 = wsum(s0), S1 = wsum(s1);
  const float o0 = EPS_LOGMU - EPSf*LN2f*flog2(fmaxf(S0, 1e-37f));
  const float o1 = EPS_LOGMU - EPSf*LN2f*flog2(fmaxf(S1, 1e-37f));
  if (lane < 2) astoref(potOut + bo + i0 + lane, lane == 0 ? o0 : o1);
}

// finalize 2 rows of one batch: sum of sqrt(N * sum_j P_ij C_ij)
__device__ __forceinline__ float fin2(
    const float4* __restrict__ J, const float4* __restrict__ P1r,
    const float* __restrict__ fArr, size_t bo, int i0, int lane)
{
  float part = 0.f;
  #pragma unroll 1
  for (int r = 0; r < 2; ++r) {
    const float4 p = P1r[bo + i0 + r];
    const float Fi = aloadf(fArr + bo + i0 + r) * SCL;
    float a0 = 0.f, a1 = 0.f;
    #pragma unroll 2
    for (int k = 0; k < CHUNKS; k += 2) {
      float4 qa = J[k * 64 + lane];
      float4 qb = J[(k + 1) * 64 + lane];
      float dxa = p.x - qa.x, dya = p.y - qa.y, dza = p.z - qa.z;
      float ca = fmaf(dxa, dxa, fmaf(dya, dya, dza * dza));
      a0 = fmaf(fexp2(fmaf(-SCL, ca, Fi + qa.w)), ca, a0);
      float dxb = p.x - qb.x, dyb = p.y - qb.y, dzb = p.z - qb.z;
      float cb = fmaf(dxb, dxb, fmaf(dyb, dyb, dzb * dzb));
      a1 = fmaf(fexp2(fmaf(-SCL, cb, Fi + qb.w)), cb, a1);
    }
    float lacc = wsum(a0 + a1);
    if (lane == 0) part += sqrtf((float)NN * lacc + 1e-12f);
  }
  return part;
}

// DUAL-BATCH deferred-wait pipeline on persistent LDS columns. Each WG
// serves b0 = wg>>5 (rows sub*32..+32) and b1 = b0^4 (rows 1024+sub*32..+32);
// 64 WGs arrive per batch barrier. All four column arrays live in LDS for
// the whole kernel (128KB); per phase only .w is rewritten (2 far loads +
// 2 ds_write_b32) — r16's fatal full-restage cost is gone. Every flag_wait
// is preceded by ~2us of independent compute on the other batch, hiding
// barrier round-trip + skew. Deadlock-free by induction: each arrival
// depends only on barriers with strictly smaller time index.
__global__ __launch_bounds__(WGS) void emd_sinkhorn_fused(
    const float4* __restrict__ P1r, const float4* __restrict__ P2r,
    float* __restrict__ fArr, float* __restrict__ gArr,
    int* __restrict__ flags, float* __restrict__ accum,
    float* __restrict__ out)
{
  __shared__ float4 JF0[NN];   // b0: {pcs2 xyz, (g-qq2)*SCL}
  __shared__ float4 JG0[NN];   // b0: {pcs1 xyz, (f-qq1)*SCL}
  __shared__ float4 JF1[NN];   // b1: same
  __shared__ float4 JG1[NN];
  __shared__ float red[NWAVES];

  const int wg = blockIdx.x, tid = threadIdx.x;
  const int b0 = wg >> 5, sub = wg & 31, b1 = b0 ^ 4;
  const int lane = tid & 63, wv = tid >> 6;
  const size_t bo0 = (size_t)b0 * NN, bo1 = (size_t)b1 * NN;
  const int j0 = tid, j1 = tid + 1024;
  const int slot0 = sub, slot1 = sub + 32;     // arrival slots in b0/b1 barriers
  const int i00 = sub * 32 + wv * 2;           // rows in b0
  const int i01 = 1024 + sub * 32 + wv * 2;    // rows in b1

  // persistent coords; qq*SCL kept in registers for .w restage
  const float4 c20a = P2r[bo0 + j0], c20b = P2r[bo0 + j1];
  const float4 c10a = P1r[bo0 + j0], c10b = P1r[bo0 + j1];
  const float4 c21a = P2r[bo1 + j0], c21b = P2r[bo1 + j1];
  const float4 c11a = P1r[bo1 + j0], c11b = P1r[bo1 + j1];
  const float q20a = c20a.w * SCL, q20b = c20b.w * SCL;
  const float q10a = c10a.w * SCL, q10b = c10b.w * SCL;
  const float q21a = c21a.w * SCL, q21b = c21b.w * SCL;
  const float q11a = c11a.w * SCL, q11b = c11b.w * SCL;
  JF0[j0] = make_float4(c20a.x, c20a.y, c20a.z, -q20a);  // t=0: g == 0
  JF0[j1] = make_float4(c20b.x, c20b.y, c20b.z, -q20b);
  JG0[j0] = make_float4(c10a.x, c10a.y, c10a.z, 0.f);
  JG0[j1] = make_float4(c10b.x, c10b.y, c10b.z, 0.f);
  JF1[j0] = make_float4(c21a.x, c21a.y, c21a.z, -q21a);
  JF1[j1] = make_float4(c21b.x, c21b.y, c21b.z, -q21b);
  JG1[j0] = make_float4(c11a.x, c11a.y, c11a.z, 0.f);
  JG1[j1] = make_float4(c11b.x, c11b.y, c11b.z, 0.f);

  // loop-invariant row constants (f-rows from pcs1, g-rows from pcs2)
  const RowC rf0 = mkRow(P1r, bo0, i00), rg0 = mkRow(P2r, bo0, i00);
  const RowC rf1 = mkRow(P1r, bo1, i01), rg1 = mkRow(P2r, bo1, i01);

  #define BARF(t, b) (flags + ((2 * (t))     * 8 + (b)) * NARR)
  #define BARG(t, b) (flags + ((2 * (t) + 1) * 8 + (b)) * NARR)

  for (int t = 0; t < MAX_ITER; ++t) {
    // f(b0): needs g(t-1, b0) — wait hidden behind prev iter's g(b1) compute
    if (t) {
      flag_wait(BARG(t - 1, b0));
      const float ga = aloadf(gArr + bo0 + j0), gb = aloadf(gArr + bo0 + j1);
      JF0[j0].w = fmaf(ga, SCL, -q20a);
      JF0[j1].w = fmaf(gb, SCL, -q20b);
    }
    __syncthreads();
    sweep2(JF0, rf0, fArr, bo0, i00, lane);
    flag_arrive(BARF(t, b0), slot0);

    // f(b1): wait hidden behind f(b0) compute
    if (t) {
      flag_wait(BARG(t - 1, b1));
      const float ga = aloadf(gArr + bo1 + j0), gb = aloadf(gArr + bo1 + j1);
      JF1[j0].w = fmaf(ga, SCL, -q21a);
      JF1[j1].w = fmaf(gb, SCL, -q21b);
    }
    __syncthreads();
    sweep2(JF1, rf1, fArr, bo1, i01, lane);
    flag_arrive(BARF(t, b1), slot1);

    // g(b0): needs f(t, b0) — wait hidden behind f(b1) compute
    flag_wait(BARF(t, b0));
    {
      const float fa = aloadf(fArr + bo0 + j0), fb = aloadf(fArr + bo0 + j1);
      JG0[j0].w = fmaf(fa, SCL, -q10a);
      JG0[j1].w = fmaf(fb, SCL, -q10b);
    }
    __syncthreads();
    sweep2(JG0, rg0, gArr, bo0, i00, lane);
    flag_arrive(BARG(t, b0), slot0);

    // g(b1): wait hidden behind g(b0) compute
    flag_wait(BARF(t, b1));
    {
      const float fa = aloadf(fArr + bo1 + j0), fb = aloadf(fArr + bo1 + j1);
      JG1[j0].w = fmaf(fa, SCL, -q11a);
      JG1[j1].w = fmaf(fb, SCL, -q11b);
    }
    __syncthreads();
    sweep2(JG1, rg1, gArr, bo1, i01, lane);
    flag_arrive(BARG(t, b1), slot1);
  }

  // ---- finalize both batch-halves
  float part = 0.f;
  flag_wait(BARG(MAX_ITER - 1, b0));
  {
    const float ga = aloadf(gArr + bo0 + j0), gb = aloadf(gArr + bo0 + j1);
    JF0[j0].w = ga * SCL;
    JF0[j1].w = gb * SCL;
  }
  __syncthreads();
  part += fin2(JF0, P1r, fArr, bo0, i00, lane);

  flag_wait(BARG(MAX_ITER - 1, b1));   // hidden behind b0 finalize
  {
    const float ga = aloadf(gArr + bo1 + j0), gb = aloadf(gArr + bo1 + j1);
    JF1[j0].w = ga * SCL;
    JF1[j1].w = gb * SCL;
  }
  __syncthreads();
  part += fin2(JF1, P1r, fArr, bo1, i01, lane);

  if (lane == 0) red[wv] = part;
  __syncthreads();
  if (tid == 0) {
    float s = 0.f;
    #pragma unroll
    for (int w = 0; w < NWAVES; ++w) s += red[w];
    atomicAdd(accum, s);
  }
  sbar(flags + 800 * NARR, GRID);      // final global barrier (counter)
  if (wg == 0 && tid == 0) out[0] = aloadf(accum) * (1.f / 16384.f);
}

extern "C" void kernel_launch(void* const* d_in, const int* in_sizes, int n_in,
                              void* d_out, int out_size, void* d_ws, size_t ws_size,
                              hipStream_t stream) {
  const float* pcs1 = (const float*)d_in[0];
  const float* pcs2 = (const float*)d_in[1];
  float* out = (float*)d_out;
  char*  base = (char*)d_ws;
  float* fArr   = (float*)base;                    // 64KB
  float* gArr   = (float*)(base + 64 * 1024);      // 64KB
  float* accum  = (float*)(base + 128 * 1024);     // 1 float
  int*   flags  = (int*)(base + 192 * 1024);       // 800x64 ints + final cnt (~205KB)
  float4* P1r   = (float4*)(base + 512 * 1024);    // 256KB
  float4* P2r   = (float4*)(base + 768 * 1024);    // 256KB

  const int nzero = 800 * NARR + 16;               // flags to zero
  const int nblk = (nzero > 2 * BB * NN ? nzero : 2 * BB * NN) / 256 + 1;
  pack_pts<<<nblk, 256, 0, stream>>>(pcs1, pcs2, P1r, P2r, flags, accum);

  // plain launch (r13/r14: coop API silently no-ops >256 blocks @1024thr;
  // 256 blocks = 1 WG/CU is trivially co-resident)
  emd_sinkhorn_fused<<<GRID, WGS, 0, stream>>>(
      P1r, P2r, fArr, gArr, flags, accum, out);
}

// Round 20
// 673.368 us; speedup vs baseline: 1.4715x; 1.4715x over previous
//
#include <hip/hip_runtime.h>

#define BB 8
#define NN 2048
#define WGS 1024
#define GRID 256
#define WG_PER_B 32           // WGs per batch
#define ROWS_WG 64            // rows per WG
#define NWAVES 16
#define RPW 4                 // rows per wave
#define CHUNKS 32             // NN/64
#define MAX_ITER 50
#define REDPAD 4160           // LDS pad: total >81920B -> 1 WG/CU -> 128 VGPR budget

// eps = 0.005; log2 domain: SCL = log2(e)/eps
constexpr float SCL       = 288.5390081777927f;
constexpr float LN2f      = 0.6931471805599453f;
constexpr float EPSf      = 0.005f;
constexpr float EPS_LOGMU = -0.03812309493079699f; // 0.005 * (-ln 2048)

#define SCOPE __HIP_MEMORY_SCOPE_AGENT

typedef float f32x2 __attribute__((ext_vector_type(2)));

__device__ __forceinline__ float aloadf(const float* p){return __hip_atomic_load(p,__ATOMIC_RELAXED,SCOPE);}
__device__ __forceinline__ void  astoref(float* p,float v){__hip_atomic_store(p,v,__ATOMIC_RELAXED,SCOPE);}
__device__ __forceinline__ int   aloadi(const int* p){return __hip_atomic_load(p,__ATOMIC_RELAXED,SCOPE);}

__device__ __forceinline__ float fexp2(float x){return __builtin_amdgcn_exp2f(x);}
__device__ __forceinline__ float flog2(float x){return __builtin_amdgcn_logf(x);}

// Packed FP32 (VOP3P). r19 lesson: ALL sources must be 64-bit VGPR PAIRS —
// a scalar VGPR src is an illegal encoding. Broadcast is done by selecting
// one half of a legal pair for BOTH output halves:
//   lo-broadcast: op_sel[src]=0, op_sel_hi[src]=0
//   hi-broadcast: op_sel[src]=1, op_sel_hi[src]=1
// (q.x,q.y) and (q.z,q.w) of a float4 LDS load are already aligned pairs.
__device__ __forceinline__ f32x2 pk_fma_lo(f32x2 a, f32x2 b, f32x2 c){ // b.lo bcast
  f32x2 d;
  asm("v_pk_fma_f32 %0, %1, %2, %3 op_sel:[0,0,0] op_sel_hi:[1,0,1]"
      : "=v"(d) : "v"(a), "v"(b), "v"(c));
  return d;
}
__device__ __forceinline__ f32x2 pk_fma_hi(f32x2 a, f32x2 b, f32x2 c){ // b.hi bcast
  f32x2 d;
  asm("v_pk_fma_f32 %0, %1, %2, %3 op_sel:[0,1,0] op_sel_hi:[1,1,1]"
      : "=v"(d) : "v"(a), "v"(b), "v"(c));
  return d;
}
__device__ __forceinline__ f32x2 pk_add_hi(f32x2 a, f32x2 b){          // b.hi bcast
  f32x2 d;
  asm("v_pk_add_f32 %0, %1, %2 op_sel:[0,1] op_sel_hi:[1,1]"
      : "=v"(d) : "v"(a), "v"(b));
  return d;
}

__device__ __forceinline__ float wsum(float v){
  #pragma unroll
  for (int d = 32; d; d >>= 1) v += __shfl_xor(v, d, 64);
  return v;
}

// FLAG-ARRAY single-use barrier (r17-proven): arrivals are plain sc1 STORES
// (no RMW serialization); waiters poll all 32 flags with one coalesced load
// per round. 0->1 monotone: no ABA/reuse races. Deadman converts deadlock
// into a fast wrong answer, never a 600s hang.
__device__ __forceinline__ void flag_arrive(int* flags, int sub){
  __syncthreads();                     // per-wave vmcnt(0) drains pot stores
  if (threadIdx.x == 0) {
    asm volatile("s_waitcnt vmcnt(0)" ::: "memory");
    __hip_atomic_store(flags + sub, 1, __ATOMIC_RELAXED, SCOPE);
  }
}
__device__ __forceinline__ void flag_wait(const int* flags){
  if (threadIdx.x < 64) {
    const int* fp = flags + (threadIdx.x & 31);
    int spins = 0;
    while (!__all(aloadi(fp) != 0)) {
      __builtin_amdgcn_s_sleep(1);
      if (++spins > (1 << 17)) break;  // deadman
    }
  }
  __syncthreads();
}
// counter barrier for the single final global sync (latency-irrelevant)
__device__ __forceinline__ void sbar(int* cnt, int nwg){
  __syncthreads();
  if (threadIdx.x == 0) {
    asm volatile("s_waitcnt vmcnt(0)" ::: "memory");
    __hip_atomic_fetch_add(cnt, 1, __ATOMIC_RELAXED, SCOPE);
    int spins = 0;
    while (aloadi(cnt) < nwg) {
      __builtin_amdgcn_s_sleep(1);
      if (++spins > (1 << 17)) break;
    }
  }
  __syncthreads();
}

// One-time prep: pack {x,y,z,|p|^2}; zero 800x32 barrier flags + final
// counter + accum.
__global__ __launch_bounds__(256) void pack_pts(
    const float* __restrict__ pcs1, const float* __restrict__ pcs2,
    float4* __restrict__ rp1, float4* __restrict__ rp2,
    int* __restrict__ flags, float* __restrict__ accum)
{
  int idx = blockIdx.x * 256 + threadIdx.x;
  if (idx == 0) *accum = 0.f;
  if (idx < 800 * 32 + 16) flags[idx] = 0;
  if (idx >= 2 * BB * NN) return;
  if (idx < BB * NN) {
    const float* s = pcs1 + 3 * (size_t)idx;
    float x = s[0], y = s[1], z = s[2];
    rp1[idx] = make_float4(x, y, z, fmaf(x, x, fmaf(y, y, z * z)));
  } else {
    int j = idx - BB * NN;
    const float* s = pcs2 + 3 * (size_t)j;
    float x = s[0], y = s[1], z = s[2];
    rp2[j] = make_float4(x, y, z, fmaf(x, x, fmaf(y, y, z * z)));
  }
}

// Fused Sinkhorn = r17 structure (persistent LDS coords, .w-only restage,
// hoisted row constants, flag barriers) + packed-f32 inner loop.
// M-free numerics proven in r15 (exp2 args in [+15,-890]; flushed terms
// lose <2^-80 relative; fmaxf backstop). pot I/O via sc1 atomics only.
__global__ __launch_bounds__(WGS) void emd_sinkhorn_fused(
    const float4* __restrict__ P1r, const float4* __restrict__ P2r,
    float* __restrict__ fArr, float* __restrict__ gArr,
    int* __restrict__ flags, float* __restrict__ accum,
    float* __restrict__ out)
{
  __shared__ float4 JF[NN];            // {x,y,z, (g_j - qq2_j)*SCL}
  __shared__ float4 JG[NN];            // {x,y,z, (f_j - qq1_j)*SCL}
  __shared__ float red[REDPAD];        // oversized: LDS occupancy pad (r5)

  const int wg = blockIdx.x, tid = threadIdx.x;
  const int b = wg / WG_PER_B, sub = wg % WG_PER_B;
  const int lane = tid & 63, wv = tid >> 6;
  const size_t bo = (size_t)b * NN;
  const int j0 = tid, j1 = tid + 1024;

  // persistent coords into LDS; per-thread qq*SCL stays in registers
  const float4 c2a = P2r[bo + j0], c2b = P2r[bo + j1];
  const float4 c1a = P1r[bo + j0], c1b = P1r[bo + j1];
  const float q2s0 = c2a.w * SCL, q2s1 = c2b.w * SCL;
  const float q1s0 = c1a.w * SCL, q1s1 = c1b.w * SCL;
  JF[j0] = make_float4(c2a.x, c2a.y, c2a.z, -q2s0);   // t=0: g == 0
  JF[j1] = make_float4(c2b.x, c2b.y, c2b.z, -q2s1);
  JG[j0] = make_float4(c1a.x, c1a.y, c1a.z, 0.f);
  JG[j1] = make_float4(c1b.x, c1b.y, c1b.z, 0.f);

  // loop-invariant row constants, packed in row-pairs (0,1) and (2,3)
  const int i0 = sub * ROWS_WG + wv * RPW;
  const float4 fp0 = P1r[bo+i0], fp1 = P1r[bo+i0+1], fp2 = P1r[bo+i0+2], fp3 = P1r[bo+i0+3];
  const float4 gp0 = P2r[bo+i0], gp1 = P2r[bo+i0+1], gp2 = P2r[bo+i0+2], gp3 = P2r[bo+i0+3];
  const f32x2 fX01x = {2.f*SCL*fp0.x, 2.f*SCL*fp1.x}, fX23x = {2.f*SCL*fp2.x, 2.f*SCL*fp3.x};
  const f32x2 fX01y = {2.f*SCL*fp0.y, 2.f*SCL*fp1.y}, fX23y = {2.f*SCL*fp2.y, 2.f*SCL*fp3.y};
  const f32x2 fX01z = {2.f*SCL*fp0.z, 2.f*SCL*fp1.z}, fX23z = {2.f*SCL*fp2.z, 2.f*SCL*fp3.z};
  const f32x2 fB01  = {-SCL*fp0.w, -SCL*fp1.w},       fB23  = {-SCL*fp2.w, -SCL*fp3.w};
  const f32x2 gX01x = {2.f*SCL*gp0.x, 2.f*SCL*gp1.x}, gX23x = {2.f*SCL*gp2.x, 2.f*SCL*gp3.x};
  const f32x2 gX01y = {2.f*SCL*gp0.y, 2.f*SCL*gp1.y}, gX23y = {2.f*SCL*gp2.y, 2.f*SCL*gp3.y};
  const f32x2 gX01z = {2.f*SCL*gp0.z, 2.f*SCL*gp1.z}, gX23z = {2.f*SCL*gp2.z, 2.f*SCL*gp3.z};
  const f32x2 gB01  = {-SCL*gp0.w, -SCL*gp1.w},       gB23  = {-SCL*gp2.w, -SCL*gp3.w};

  #define BARF(t) (flags + ((2 * (t))     * 8 + b) * 32)
  #define BARG(t) (flags + ((2 * (t) + 1) * 8 + b) * 32)

  for (int t = 0; t < MAX_ITER; ++t) {
    // ---- f-phase: cols JF (pcs2 + g), rows pcs1
    if (t) {
      flag_wait(BARG(t - 1));
      const float ga = aloadf(gArr + bo + j0), gb = aloadf(gArr + bo + j1);
      JF[j0].w = fmaf(ga, SCL, -q2s0);
      JF[j1].w = fmaf(gb, SCL, -q2s1);
    }
    __syncthreads();
    {
      float s0 = 0.f, s1 = 0.f, s2 = 0.f, s3 = 0.f;
      #pragma unroll 4
      for (int k = 0; k < CHUNKS; ++k) {
        float4 q = JF[k * 64 + lane];
        f32x2 qxy = {q.x, q.y}, qzw = {q.z, q.w};   // aligned subpairs of the b128 load
        f32x2 eA = pk_fma_lo(fX01x, qxy, pk_fma_hi(fX01y, qxy,
                     pk_fma_lo(fX01z, qzw, pk_add_hi(fB01, qzw))));
        f32x2 eB = pk_fma_lo(fX23x, qxy, pk_fma_hi(fX23y, qxy,
                     pk_fma_lo(fX23z, qzw, pk_add_hi(fB23, qzw))));
        s0 += fexp2(eA.x); s1 += fexp2(eA.y);
        s2 += fexp2(eB.x); s3 += fexp2(eB.y);
      }
      const float S0 = wsum(s0), S1 = wsum(s1), S2 = wsum(s2), S3 = wsum(s3);
      const float o0 = EPS_LOGMU - EPSf*LN2f*flog2(fmaxf(S0, 1e-37f));
      const float o1 = EPS_LOGMU - EPSf*LN2f*flog2(fmaxf(S1, 1e-37f));
      const float o2 = EPS_LOGMU - EPSf*LN2f*flog2(fmaxf(S2, 1e-37f));
      const float o3 = EPS_LOGMU - EPSf*LN2f*flog2(fmaxf(S3, 1e-37f));
      const float oo = lane == 0 ? o0 : (lane == 1 ? o1 : (lane == 2 ? o2 : o3));
      if (lane < 4) astoref(fArr + bo + i0 + lane, oo);
    }
    flag_arrive(BARF(t), sub);

    // ---- g-phase: cols JG (pcs1 + f), rows pcs2
    flag_wait(BARF(t));
    {
      const float fa = aloadf(fArr + bo + j0), fb = aloadf(fArr + bo + j1);
      JG[j0].w = fmaf(fa, SCL, -q1s0);
      JG[j1].w = fmaf(fb, SCL, -q1s1);
    }
    __syncthreads();
    {
      float s0 = 0.f, s1 = 0.f, s2 = 0.f, s3 = 0.f;
      #pragma unroll 4
      for (int k = 0; k < CHUNKS; ++k) {
        float4 q = JG[k * 64 + lane];
        f32x2 qxy = {q.x, q.y}, qzw = {q.z, q.w};
        f32x2 eA = pk_fma_lo(gX01x, qxy, pk_fma_hi(gX01y, qxy,
                     pk_fma_lo(gX01z, qzw, pk_add_hi(gB01, qzw))));
        f32x2 eB = pk_fma_lo(gX23x, qxy, pk_fma_hi(gX23y, qxy,
                     pk_fma_lo(gX23z, qzw, pk_add_hi(gB23, qzw))));
        s0 += fexp2(eA.x); s1 += fexp2(eA.y);
        s2 += fexp2(eB.x); s3 += fexp2(eB.y);
      }
      const float S0 = wsum(s0), S1 = wsum(s1), S2 = wsum(s2), S3 = wsum(s3);
      const float o0 = EPS_LOGMU - EPSf*LN2f*flog2(fmaxf(S0, 1e-37f));
      const float o1 = EPS_LOGMU - EPSf*LN2f*flog2(fmaxf(S1, 1e-37f));
      const float o2 = EPS_LOGMU - EPSf*LN2f*flog2(fmaxf(S2, 1e-37f));
      const float o3 = EPS_LOGMU - EPSf*LN2f*flog2(fmaxf(S3, 1e-37f));
      const float oo = lane == 0 ? o0 : (lane == 1 ? o1 : (lane == 2 ? o2 : o3));
      if (lane < 4) astoref(gArr + bo + i0 + lane, oo);
    }
    flag_arrive(BARG(t), sub);
  }

  // ---- finalize: dist_i = N * sum_j exp2((f_i+g_j-C_ij)*SCL) * C_ij
  flag_wait(BARG(MAX_ITER - 1));
  {
    const float ga = aloadf(gArr + bo + j0), gb = aloadf(gArr + bo + j1);
    JF[j0].w = ga * SCL;                 // coords persist; w := g*SCL
    JF[j1].w = gb * SCL;
  }
  __syncthreads();

  const float4 prs[RPW] = { fp0, fp1, fp2, fp3 };
  float part = 0.f;
  #pragma unroll
  for (int r = 0; r < RPW; ++r) {
    const float4 p = prs[r];
    const float Fi = aloadf(fArr + bo + i0 + r) * SCL;
    float a0 = 0.f, a1 = 0.f;
    #pragma unroll 2
    for (int k = 0; k < CHUNKS; k += 2) {
      float4 qa = JF[k * 64 + lane];
      float4 qb = JF[(k + 1) * 64 + lane];
      float dxa = p.x - qa.x, dya = p.y - qa.y, dza = p.z - qa.z;
      float ca = fmaf(dxa, dxa, fmaf(dya, dya, dza * dza));
      a0 = fmaf(fexp2(fmaf(-SCL, ca, Fi + qa.w)), ca, a0);
      float dxb = p.x - qb.x, dyb = p.y - qb.y, dzb = p.z - qb.z;
      float cb = fmaf(dxb, dxb, fmaf(dyb, dyb, dzb * dzb));
      a1 = fmaf(fexp2(fmaf(-SCL, cb, Fi + qb.w)), cb, a1);
    }
    float lacc = wsum(a0 + a1);
    if (lane == 0) part += sqrtf((float)NN * lacc + 1e-12f);
  }
  if (lane == 0) red[wv] = part;
  __syncthreads();
  if (tid == 0) {
    float s = 0.f;
    #pragma unroll
    for (int w = 0; w < NWAVES; ++w) s += red[w];
    atomicAdd(accum, s);
  }
  sbar(flags + 800 * 32, GRID);          // final global barrier (counter)
  if (wg == 0 && tid == 0) out[0] = aloadf(accum) * (1.f / 16384.f);
}

extern "C" void kernel_launch(void* const* d_in, const int* in_sizes, int n_in,
                              void* d_out, int out_size, void* d_ws, size_t ws_size,
                              hipStream_t stream) {
  const float* pcs1 = (const float*)d_in[0];
  const float* pcs2 = (const float*)d_in[1];
  float* out = (float*)d_out;
  char*  base = (char*)d_ws;
  float* fArr   = (float*)base;                    // 64KB
  float* gArr   = (float*)(base + 64 * 1024);      // 64KB
  float* accum  = (float*)(base + 128 * 1024);     // 1 float
  int*   flags  = (int*)(base + 192 * 1024);       // 800x32 ints + final cnt
  float4* P1r   = (float4*)(base + 512 * 1024);    // 256KB
  float4* P2r   = (float4*)(base + 768 * 1024);    // 256KB

  pack_pts<<<(2 * BB * NN + 255) / 256, 256, 0, stream>>>(
      pcs1, pcs2, P1r, P2r, flags, accum);

  // plain launch (r13/r14: coop API silently no-ops >256 blocks @1024thr;
  // 256 blocks = 1 WG/CU is trivially co-resident)
  emd_sinkhorn_fused<<<GRID, WGS, 0, stream>>>(
      P1r, P2r, fArr, gArr, flags, accum, out);
}

// Round 21
// 648.413 us; speedup vs baseline: 1.5281x; 1.0385x over previous
//
#include <hip/hip_runtime.h>

#define BB 8
#define NN 2048
#define WGS 1024
#define GRID 256
#define WG_PER_B 32           // WGs per batch
#define ROWS_WG 64            // rows per WG
#define NWAVES 16
#define RPW 4                 // rows per wave
#define CHUNKS 32             // NN/64
#define MAX_ITER 50
#define REDPAD 4160           // LDS pad: total >81920B -> 1 WG/CU -> 128 VGPR budget

// eps = 0.005; log2 domain: SCL = log2(e)/eps
constexpr float SCL       = 288.5390081777927f;
constexpr float LN2f      = 0.6931471805599453f;
constexpr float EPSf      = 0.005f;
constexpr float EPS_LOGMU = -0.03812309493079699f; // 0.005 * (-ln 2048)

#define SCOPE __HIP_MEMORY_SCOPE_AGENT

typedef float f32x2 __attribute__((ext_vector_type(2)));

__device__ __forceinline__ float aloadf(const float* p){return __hip_atomic_load(p,__ATOMIC_RELAXED,SCOPE);}
__device__ __forceinline__ void  astoref(float* p,float v){__hip_atomic_store(p,v,__ATOMIC_RELAXED,SCOPE);}
__device__ __forceinline__ int   aloadi(const int* p){return __hip_atomic_load(p,__ATOMIC_RELAXED,SCOPE);}

__device__ __forceinline__ float fexp2(float x){return __builtin_amdgcn_exp2f(x);}
__device__ __forceinline__ float flog2(float x){return __builtin_amdgcn_logf(x);}

// Packed FP32 (VOP3P). r19 lesson: ALL sources must be 64-bit VGPR PAIRS.
// Broadcast selects one half of a legal pair for BOTH output halves:
//   lo: op_sel[src]=0, op_sel_hi[src]=0 ; hi: op_sel[src]=1, op_sel_hi[src]=1
// (q.x,q.y) and (q.z,q.w) of a float4 LDS load are aligned pairs.
__device__ __forceinline__ f32x2 pk_fma_lo(f32x2 a, f32x2 b, f32x2 c){ // b.lo bcast
  f32x2 d;
  asm("v_pk_fma_f32 %0, %1, %2, %3 op_sel:[0,0,0] op_sel_hi:[1,0,1]"
      : "=v"(d) : "v"(a), "v"(b), "v"(c));
  return d;
}
__device__ __forceinline__ f32x2 pk_fma_hi(f32x2 a, f32x2 b, f32x2 c){ // b.hi bcast
  f32x2 d;
  asm("v_pk_fma_f32 %0, %1, %2, %3 op_sel:[0,1,0] op_sel_hi:[1,1,1]"
      : "=v"(d) : "v"(a), "v"(b), "v"(c));
  return d;
}
__device__ __forceinline__ f32x2 pk_add_hi(f32x2 a, f32x2 b){          // b.hi bcast
  f32x2 d;
  asm("v_pk_add_f32 %0, %1, %2 op_sel:[0,1] op_sel_hi:[1,1]"
      : "=v"(d) : "v"(a), "v"(b));
  return d;
}

__device__ __forceinline__ float wsum(float v){
  #pragma unroll
  for (int d = 32; d; d >>= 1) v += __shfl_xor(v, d, 64);
  return v;
}

// FLAG-ARRAY single-use barrier (r17-proven): arrivals are plain sc1 STORES
// (no RMW serialization); waiters poll all 32 flags with one coalesced load
// per round. 0->1 monotone: no ABA/reuse races. Deadman converts deadlock
// into a fast wrong answer, never a 600s hang.
__device__ __forceinline__ void flag_arrive(int* flags, int sub){
  __syncthreads();                     // per-wave vmcnt(0) drains pot stores
  if (threadIdx.x == 0) {
    asm volatile("s_waitcnt vmcnt(0)" ::: "memory");
    __hip_atomic_store(flags + sub, 1, __ATOMIC_RELAXED, SCOPE);
  }
}
__device__ __forceinline__ void flag_wait(const int* flags){
  if (threadIdx.x < 64) {
    const int* fp = flags + (threadIdx.x & 31);
    int spins = 0;
    while (!__all(aloadi(fp) != 0)) {
      __builtin_amdgcn_s_sleep(1);
      if (++spins > (1 << 17)) break;  // deadman
    }
  }
  __syncthreads();
}
// counter barrier for the single final global sync (latency-irrelevant)
__device__ __forceinline__ void sbar(int* cnt, int nwg){
  __syncthreads();
  if (threadIdx.x == 0) {
    asm volatile("s_waitcnt vmcnt(0)" ::: "memory");
    __hip_atomic_fetch_add(cnt, 1, __ATOMIC_RELAXED, SCOPE);
    int spins = 0;
    while (aloadi(cnt) < nwg) {
      __builtin_amdgcn_s_sleep(1);
      if (++spins > (1 << 17)) break;
    }
  }
  __syncthreads();
}

// One-time prep: pack {x,y,z,|p|^2}; zero 800x32 barrier flags + final
// counter + accum.
__global__ __launch_bounds__(256) void pack_pts(
    const float* __restrict__ pcs1, const float* __restrict__ pcs2,
    float4* __restrict__ rp1, float4* __restrict__ rp2,
    int* __restrict__ flags, float* __restrict__ accum)
{
  int idx = blockIdx.x * 256 + threadIdx.x;
  if (idx == 0) *accum = 0.f;
  if (idx < 800 * 32 + 16) flags[idx] = 0;
  if (idx >= 2 * BB * NN) return;
  if (idx < BB * NN) {
    const float* s = pcs1 + 3 * (size_t)idx;
    float x = s[0], y = s[1], z = s[2];
    rp1[idx] = make_float4(x, y, z, fmaf(x, x, fmaf(y, y, z * z)));
  } else {
    int j = idx - BB * NN;
    const float* s = pcs2 + 3 * (size_t)j;
    float x = s[0], y = s[1], z = s[2];
    rp2[j] = make_float4(x, y, z, fmaf(x, x, fmaf(y, y, z * z)));
  }
}

// Fused Sinkhorn = r20 (persistent LDS coords, .w-only restage, hoisted
// packed row constants, flag barriers, packed-f32 inner loop) + XCD-LOCAL
// BATCH MAPPING: b = wg & 7 (not wg/32). MI355X dispatches blocks
// round-robin across the 8 XCDs, so all 32 WGs of batch b land on XCD b —
// barrier flags, fArr/gArr exchange, and restage loads become XCD-local L2
// traffic (~0.2us) instead of cross-die coherence round-trips (~0.7-1us).
// Correctness is placement-independent (atomics are atomics); only latency
// changes, so a different dispatch mapping = clean null, not a failure.
__global__ __launch_bounds__(WGS) void emd_sinkhorn_fused(
    const float4* __restrict__ P1r, const float4* __restrict__ P2r,
    float* __restrict__ fArr, float* __restrict__ gArr,
    int* __restrict__ flags, float* __restrict__ accum,
    float* __restrict__ out)
{
  __shared__ float4 JF[NN];            // {x,y,z, (g_j - qq2_j)*SCL}
  __shared__ float4 JG[NN];            // {x,y,z, (f_j - qq1_j)*SCL}
  __shared__ float red[REDPAD];        // oversized: LDS occupancy pad (r5)

  const int wg = blockIdx.x, tid = threadIdx.x;
  const int b = wg & 7, sub = wg >> 3;           // XCD-local batch mapping
  const int lane = tid & 63, wv = tid >> 6;
  const size_t bo = (size_t)b * NN;
  const int j0 = tid, j1 = tid + 1024;

  // persistent coords into LDS; per-thread qq*SCL stays in registers
  const float4 c2a = P2r[bo + j0], c2b = P2r[bo + j1];
  const float4 c1a = P1r[bo + j0], c1b = P1r[bo + j1];
  const float q2s0 = c2a.w * SCL, q2s1 = c2b.w * SCL;
  const float q1s0 = c1a.w * SCL, q1s1 = c1b.w * SCL;
  JF[j0] = make_float4(c2a.x, c2a.y, c2a.z, -q2s0);   // t=0: g == 0
  JF[j1] = make_float4(c2b.x, c2b.y, c2b.z, -q2s1);
  JG[j0] = make_float4(c1a.x, c1a.y, c1a.z, 0.f);
  JG[j1] = make_float4(c1b.x, c1b.y, c1b.z, 0.f);

  // loop-invariant row constants, packed in row-pairs (0,1) and (2,3)
  const int i0 = sub * ROWS_WG + wv * RPW;
  const float4 fp0 = P1r[bo+i0], fp1 = P1r[bo+i0+1], fp2 = P1r[bo+i0+2], fp3 = P1r[bo+i0+3];
  const float4 gp0 = P2r[bo+i0], gp1 = P2r[bo+i0+1], gp2 = P2r[bo+i0+2], gp3 = P2r[bo+i0+3];
  const f32x2 fX01x = {2.f*SCL*fp0.x, 2.f*SCL*fp1.x}, fX23x = {2.f*SCL*fp2.x, 2.f*SCL*fp3.x};
  const f32x2 fX01y = {2.f*SCL*fp0.y, 2.f*SCL*fp1.y}, fX23y = {2.f*SCL*fp2.y, 2.f*SCL*fp3.y};
  const f32x2 fX01z = {2.f*SCL*fp0.z, 2.f*SCL*fp1.z}, fX23z = {2.f*SCL*fp2.z, 2.f*SCL*fp3.z};
  const f32x2 fB01  = {-SCL*fp0.w, -SCL*fp1.w},       fB23  = {-SCL*fp2.w, -SCL*fp3.w};
  const f32x2 gX01x = {2.f*SCL*gp0.x, 2.f*SCL*gp1.x}, gX23x = {2.f*SCL*gp2.x, 2.f*SCL*gp3.x};
  const f32x2 gX01y = {2.f*SCL*gp0.y, 2.f*SCL*gp1.y}, gX23y = {2.f*SCL*gp2.y, 2.f*SCL*gp3.y};
  const f32x2 gX01z = {2.f*SCL*gp0.z, 2.f*SCL*gp1.z}, gX23z = {2.f*SCL*gp2.z, 2.f*SCL*gp3.z};
  const f32x2 gB01  = {-SCL*gp0.w, -SCL*gp1.w},       gB23  = {-SCL*gp2.w, -SCL*gp3.w};

  #define BARF(t) (flags + ((2 * (t))     * 8 + b) * 32)
  #define BARG(t) (flags + ((2 * (t) + 1) * 8 + b) * 32)

  for (int t = 0; t < MAX_ITER; ++t) {
    // ---- f-phase: cols JF (pcs2 + g), rows pcs1
    if (t) {
      flag_wait(BARG(t - 1));
      const float ga = aloadf(gArr + bo + j0), gb = aloadf(gArr + bo + j1);
      JF[j0].w = fmaf(ga, SCL, -q2s0);
      JF[j1].w = fmaf(gb, SCL, -q2s1);
    }
    __syncthreads();
    {
      float s0 = 0.f, s1 = 0.f, s2 = 0.f, s3 = 0.f;
      #pragma unroll 4
      for (int k = 0; k < CHUNKS; ++k) {
        float4 q = JF[k * 64 + lane];
        f32x2 qxy = {q.x, q.y}, qzw = {q.z, q.w};   // aligned subpairs of the b128 load
        f32x2 eA = pk_fma_lo(fX01x, qxy, pk_fma_hi(fX01y, qxy,
                     pk_fma_lo(fX01z, qzw, pk_add_hi(fB01, qzw))));
        f32x2 eB = pk_fma_lo(fX23x, qxy, pk_fma_hi(fX23y, qxy,
                     pk_fma_lo(fX23z, qzw, pk_add_hi(fB23, qzw))));
        s0 += fexp2(eA.x); s1 += fexp2(eA.y);
        s2 += fexp2(eB.x); s3 += fexp2(eB.y);
      }
      const float S0 = wsum(s0), S1 = wsum(s1), S2 = wsum(s2), S3 = wsum(s3);
      const float o0 = EPS_LOGMU - EPSf*LN2f*flog2(fmaxf(S0, 1e-37f));
      const float o1 = EPS_LOGMU - EPSf*LN2f*flog2(fmaxf(S1, 1e-37f));
      const float o2 = EPS_LOGMU - EPSf*LN2f*flog2(fmaxf(S2, 1e-37f));
      const float o3 = EPS_LOGMU - EPSf*LN2f*flog2(fmaxf(S3, 1e-37f));
      const float oo = lane == 0 ? o0 : (lane == 1 ? o1 : (lane == 2 ? o2 : o3));
      if (lane < 4) astoref(fArr + bo + i0 + lane, oo);
    }
    flag_arrive(BARF(t), sub);

    // ---- g-phase: cols JG (pcs1 + f), rows pcs2
    flag_wait(BARF(t));
    {
      const float fa = aloadf(fArr + bo + j0), fb = aloadf(fArr + bo + j1);
      JG[j0].w = fmaf(fa, SCL, -q1s0);
      JG[j1].w = fmaf(fb, SCL, -q1s1);
    }
    __syncthreads();
    {
      float s0 = 0.f, s1 = 0.f, s2 = 0.f, s3 = 0.f;
      #pragma unroll 4
      for (int k = 0; k < CHUNKS; ++k) {
        float4 q = JG[k * 64 + lane];
        f32x2 qxy = {q.x, q.y}, qzw = {q.z, q.w};
        f32x2 eA = pk_fma_lo(gX01x, qxy, pk_fma_hi(gX01y, qxy,
                     pk_fma_lo(gX01z, qzw, pk_add_hi(gB01, qzw))));
        f32x2 eB = pk_fma_lo(gX23x, qxy, pk_fma_hi(gX23y, qxy,
                     pk_fma_lo(gX23z, qzw, pk_add_hi(gB23, qzw))));
        s0 += fexp2(eA.x); s1 += fexp2(eA.y);
        s2 += fexp2(eB.x); s3 += fexp2(eB.y);
      }
      const float S0 = wsum(s0), S1 = wsum(s1), S2 = wsum(s2), S3 = wsum(s3);
      const float o0 = EPS_LOGMU - EPSf*LN2f*flog2(fmaxf(S0, 1e-37f));
      const float o1 = EPS_LOGMU - EPSf*LN2f*flog2(fmaxf(S1, 1e-37f));
      const float o2 = EPS_LOGMU - EPSf*LN2f*flog2(fmaxf(S2, 1e-37f));
      const float o3 = EPS_LOGMU - EPSf*LN2f*flog2(fmaxf(S3, 1e-37f));
      const float oo = lane == 0 ? o0 : (lane == 1 ? o1 : (lane == 2 ? o2 : o3));
      if (lane < 4) astoref(gArr + bo + i0 + lane, oo);
    }
    flag_arrive(BARG(t), sub);
  }

  // ---- finalize: dist_i = N * sum_j exp2((f_i+g_j-C_ij)*SCL) * C_ij
  flag_wait(BARG(MAX_ITER - 1));
  {
    const float ga = aloadf(gArr + bo + j0), gb = aloadf(gArr + bo + j1);
    JF[j0].w = ga * SCL;                 // coords persist; w := g*SCL
    JF[j1].w = gb * SCL;
  }
  __syncthreads();

  const float4 prs[RPW] = { fp0, fp1, fp2, fp3 };
  float part = 0.f;
  #pragma unroll
  for (int r = 0; r < RPW; ++r) {
    const float4 p = prs[r];
    const float Fi = aloadf(fArr + bo + i0 + r) * SCL;
    float a0 = 0.f, a1 = 0.f;
    #pragma unroll 2
    for (int k = 0; k < CHUNKS; k += 2) {
      float4 qa = JF[k * 64 + lane];
      float4 qb = JF[(k + 1) * 64 + lane];
      float dxa = p.x - qa.x, dya = p.y - qa.y, dza = p.z - qa.z;
      float ca = fmaf(dxa, dxa, fmaf(dya, dya, dza * dza));
      a0 = fmaf(fexp2(fmaf(-SCL, ca, Fi + qa.w)), ca, a0);
      float dxb = p.x - qb.x, dyb = p.y - qb.y, dzb = p.z - qb.z;
      float cb = fmaf(dxb, dxb, fmaf(dyb, dyb, dzb * dzb));
      a1 = fmaf(fexp2(fmaf(-SCL, cb, Fi + qb.w)), cb, a1);
    }
    float lacc = wsum(a0 + a1);
    if (lane == 0) part += sqrtf((float)NN * lacc + 1e-12f);
  }
  if (lane == 0) red[wv] = part;
  __syncthreads();
  if (tid == 0) {
    float s = 0.f;
    #pragma unroll
    for (int w = 0; w < NWAVES; ++w) s += red[w];
    atomicAdd(accum, s);
  }
  sbar(flags + 800 * 32, GRID);          // final global barrier (counter)
  if (wg == 0 && tid == 0) out[0] = aloadf(accum) * (1.f / 16384.f);
}

extern "C" void kernel_launch(void* const* d_in, const int* in_sizes, int n_in,
                              void* d_out, int out_size, void* d_ws, size_t ws_size,
                              hipStream_t stream) {
  const float* pcs1 = (const float*)d_in[0];
  const float* pcs2 = (const float*)d_in[1];
  float* out = (float*)d_out;
  char*  base = (char*)d_ws;
  float* fArr   = (float*)base;                    // 64KB
  float* gArr   = (float*)(base + 64 * 1024);      // 64KB
  float* accum  = (float*)(base + 128 * 1024);     // 1 float
  int*   flags  = (int*)(base + 192 * 1024);       // 800x32 ints + final cnt
  float4* P1r   = (float4*)(base + 512 * 1024);    // 256KB
  float4* P2r   = (float4*)(base + 768 * 1024);    // 256KB

  pack_pts<<<(2 * BB * NN + 255) / 256, 256, 0, stream>>>(
      pcs1, pcs2, P1r, P2r, flags, accum);

  // plain launch (r13/r14: coop API silently no-ops >256 blocks @1024thr;
  // 256 blocks = 1 WG/CU is trivially co-resident)
  emd_sinkhorn_fused<<<GRID, WGS, 0, stream>>>(
      P1r, P2r, fArr, gArr, flags, accum, out);
}